// Round 9
// baseline (79.835 us; speedup 1.0000x reference)
//
#include <hip/hip_runtime.h>

#define IMG 28
#define FLATK 784     // 28*28
#define OHW 26
#define FLAT 676      // 26*26
#define HID 100
#define NCLS 10
#define KP 832        // K padded to 13*64
#define NSTEPS 13     // K-steps of 64
#define BM 128        // rows per block (4 waves x 32 rows)
#define ABUF 32768    // one A buffer: 128 rows x 64 f32

typedef __attribute__((ext_vector_type(8))) short bfrag;   // 8 bf16 (4 VGPR)
typedef __attribute__((ext_vector_type(4))) float f32x4;
typedef __attribute__((ext_vector_type(4))) unsigned int u32x4;

__device__ __forceinline__ unsigned short f2bf(float f) {
    unsigned u = __float_as_uint(f);
    u = (u + 0x7fffu + ((u >> 16) & 1u)) >> 16;   // RNE
    return (unsigned short)u;
}

// Kernel 1: fold conv into fc1 -> bf16 W1eff [128 n][832 k] (zero-padded),
// and w2 -> bf16 [16 n][128 k] (zero-padded).
__global__ void build_weights(const float* __restrict__ conv_w,
                              const float* __restrict__ w1,
                              const float* __restrict__ w2,
                              unsigned short* __restrict__ w1b,
                              unsigned short* __restrict__ w2b) {
    int idx = blockIdx.x * blockDim.x + threadIdx.x;
    if (idx < 128 * KP) {
        int n = idx / KP, k = idx - n * KP;
        float val = 0.f;
        if (n < HID && k < FLATK) {
            int qr = k / IMG, qc = k % IMG;
            #pragma unroll
            for (int i = 0; i < 3; ++i) {
                int r = qr - i;
                if (r < 0 || r >= OHW) continue;
                #pragma unroll
                for (int j = 0; j < 3; ++j) {
                    int c = qc - j;
                    if (c < 0 || c >= OHW) continue;
                    val += conv_w[i * 3 + j] * w1[n * FLAT + r * OHW + c];
                }
            }
        }
        w1b[idx] = f2bf(val);
    } else {
        int t = idx - 128 * KP;
        if (t < 16 * 128) {
            int n = t >> 7, k = t & 127;
            float v = (n < NCLS && k < HID) ? w2[n * HID + k] : 0.f;
            w2b[t] = f2bf(v);
        }
    }
}

// Kernel 2: R8 template with BK 32->64 (13 steps instead of 25 -- halves the
// per-step drain/barrier count, doubles staged bytes in flight). Sync
// semantics unchanged from the verified template: vmcnt(0)+__syncthreads
// per step, two LDS buffers, B direct from L2-hot w1b, cvt_pk conversion.
__global__ __launch_bounds__(256) void fused_fwd(
    const float* __restrict__ x,              // [65536][784] f32
    const unsigned short* __restrict__ w1b,   // [128][832] bf16
    const float* __restrict__ b1,             // [100]
    const unsigned short* __restrict__ w2b,   // [16][128] bf16
    const float* __restrict__ b2,             // [10]
    float* __restrict__ out)                  // [65536][10] f32
{
    // A double buffer: 2 x [128 rows][64 f32] = 2 x 32 KB.
    // h1 (after main loop, aliased): [128][136] bf16 = 34816 B.
    __shared__ char smem[2 * ABUF] __attribute__((aligned(128)));

    const int tid  = threadIdx.x;
    const int lane = tid & 63;
    const int wv   = tid >> 6;
    const int r15  = lane & 15;
    const int khi  = lane >> 4;      // 0..3
    const int row0 = blockIdx.x * BM;

    f32x4 acc[2][8];
    #pragma unroll
    for (int m = 0; m < 2; ++m)
        #pragma unroll
        for (int n = 0; n < 8; ++n)
            acc[m][n] = f32x4{0.f, 0.f, 0.f, 0.f};

    // staging: one buffer = 128 rows x 256 B; chunk = 4 rows x 256 B = 1024 B.
    // dest phys = chunk*1024 + lane*16 (linear, required by global_load_lds);
    // logical 16B-unit u of row r lives at phys unit u ^ (r&7)  =>  source
    // col is pre-swizzled per lane.
    const int lrow = lane >> 4;      // row within 4-row chunk (0..3)
    auto stage = [&](int s, unsigned bufoff) {
        #pragma unroll
        for (int c = 0; c < 8; ++c) {
            int chunk = (wv << 3) + c;           // 0..31
            int r = (chunk << 2) + lrow;         // global row in tile
            int cfl = ((lane & 15) ^ (r & 7)) << 2;   // source col (floats)
            int col = (s << 6) + cfl;
            if (col >= FLATK) col -= FLATK;      // pad lanes: in-row garbage, B=0 there
            const float* g = x + (size_t)(row0 + r) * FLATK + col;
            __builtin_amdgcn_global_load_lds(
                (const __attribute__((address_space(1))) void*)g,
                (__attribute__((address_space(3))) void*)(smem + bufoff + chunk * 1024),
                16, 0, 0);
        }
    };

    auto compute = [&](int s, unsigned bufoff) {
        const int k0 = s << 6;
        #pragma unroll
        for (int kc = 0; kc < 2; ++kc) {
            // A fragments: lane holds row (lane&15) of slab, k = khi*8 .. +8
            bfrag af[2];
            #pragma unroll
            for (int mf = 0; mf < 2; ++mf) {
                int r = (wv << 5) + (mf << 4) + r15;
                unsigned alog = ((unsigned)r << 8) + (unsigned)(kc << 7) + (unsigned)(khi << 5);
                unsigned sw = (unsigned)((r & 7) << 4);
                f32x4 lo = *(const f32x4*)(smem + bufoff + (alog ^ sw));
                f32x4 hi = *(const f32x4*)(smem + bufoff + ((alog + 16u) ^ sw));
                union { u32x4 u; bfrag b; } a;
                asm("v_cvt_pk_bf16_f32 %0, %1, %2" : "=v"(a.u.x) : "v"(lo.x), "v"(lo.y));
                asm("v_cvt_pk_bf16_f32 %0, %1, %2" : "=v"(a.u.y) : "v"(lo.z), "v"(lo.w));
                asm("v_cvt_pk_bf16_f32 %0, %1, %2" : "=v"(a.u.z) : "v"(hi.x), "v"(hi.y));
                asm("v_cvt_pk_bf16_f32 %0, %1, %2" : "=v"(a.u.w) : "v"(hi.z), "v"(hi.w));
                af[mf] = a.b;
            }
            // B fragments straight from L2-resident w1b
            #pragma unroll
            for (int nt = 0; nt < 8; ++nt) {
                const bfrag bw = *(const bfrag*)(w1b + (size_t)((nt << 4) + r15) * KP
                                                 + k0 + (kc << 5) + (khi << 3));
                acc[0][nt] = __builtin_amdgcn_mfma_f32_16x16x32_bf16(af[0], bw, acc[0][nt], 0, 0, 0);
                acc[1][nt] = __builtin_amdgcn_mfma_f32_16x16x32_bf16(af[1], bw, acc[1][nt], 0, 0, 0);
            }
        }
    };

    stage(0, 0u);
    #pragma unroll 2
    for (int s = 0; s < NSTEPS; ++s) {
        unsigned cur = (s & 1) ? (unsigned)ABUF : 0u;
        asm volatile("s_waitcnt vmcnt(0)" ::: "memory");  // own staging DMA done
        __syncthreads();                                   // everyone's staging done
        if (s + 1 < NSTEPS) stage(s + 1, cur ^ (unsigned)ABUF);
        compute(s, cur);
    }
    __syncthreads();   // all A reads done before aliasing smem with h1

    // epilogue 1: bias + relu -> bf16 h1 in LDS [128][136]
    unsigned short (*H1)[136] = (unsigned short (*)[136])smem;
    #pragma unroll
    for (int nt = 0; nt < 8; ++nt) {
        int col = (nt << 4) + r15;
        float bias = (col < HID) ? b1[col] : 0.f;
        #pragma unroll
        for (int mf = 0; mf < 2; ++mf) {
            int rbase = (wv << 5) + (mf << 4) + (khi << 2);
            #pragma unroll
            for (int q = 0; q < 4; ++q) {
                float v = acc[mf][nt][q] + bias;
                H1[rbase + q][col] = f2bf(fmaxf(v, 0.f));
            }
        }
    }
    __syncthreads();

    // layer 2: [128 rows] x [16 cols] over K=128 (pad cols/k are exact zeros)
    f32x4 acc2[2] = {f32x4{0.f,0.f,0.f,0.f}, f32x4{0.f,0.f,0.f,0.f}};
    #pragma unroll
    for (int ks = 0; ks < 4; ++ks) {
        const bfrag bw = *(const bfrag*)(w2b + r15 * 128 + (ks << 5) + (khi << 3));
        #pragma unroll
        for (int mf = 0; mf < 2; ++mf) {
            int r = (wv << 5) + (mf << 4) + r15;
            const bfrag ah = *(const bfrag*)&H1[r][(ks << 5) + (khi << 3)];
            acc2[mf] = __builtin_amdgcn_mfma_f32_16x16x32_bf16(ah, bw, acc2[mf], 0, 0, 0);
        }
    }

    if (r15 < NCLS) {
        float bias2 = b2[r15];
        #pragma unroll
        for (int mf = 0; mf < 2; ++mf) {
            int rbase = row0 + (wv << 5) + (mf << 4) + (khi << 2);
            #pragma unroll
            for (int q = 0; q < 4; ++q)
                out[(size_t)(rbase + q) * NCLS + r15] = acc2[mf][q] + bias2;
        }
    }
}

extern "C" void kernel_launch(void* const* d_in, const int* in_sizes, int n_in,
                              void* d_out, int out_size, void* d_ws, size_t ws_size,
                              hipStream_t stream) {
    const float* x      = (const float*)d_in[0];
    const float* conv_w = (const float*)d_in[1];
    const float* w1     = (const float*)d_in[2];
    const float* b1     = (const float*)d_in[3];
    const float* w2     = (const float*)d_in[4];
    const float* b2     = (const float*)d_in[5];
    float* out = (float*)d_out;

    unsigned short* w1b = (unsigned short*)d_ws;   // 128*832*2 = 208 KB
    unsigned short* w2b = w1b + 128 * KP;          // 16*128*2  = 4 KB

    build_weights<<<(128 * KP + 16 * 128 + 255) / 256, 256, 0, stream>>>(conv_w, w1, w2, w1b, w2b);
    fused_fwd<<<65536 / BM, 256, 0, stream>>>(x, w1b, b1, w2b, b2, out);
}

// Round 11
// 59.399 us; speedup vs baseline: 1.3441x; 1.3441x over previous
//
#include <hip/hip_runtime.h>

#define IMG 28
#define FLATK 784     // 28*28
#define OHW 26
#define FLAT 676      // 26*26
#define HID 100
#define NCLS 10
#define KP 800        // K padded to 25*32
#define BM 128        // rows per block (4 waves x 32 rows, mf=2)

typedef __attribute__((ext_vector_type(8))) short bfrag;   // 8 bf16 (4 VGPR)
typedef __attribute__((ext_vector_type(4))) float f32x4;
typedef __attribute__((ext_vector_type(4))) unsigned int u32x4;

__device__ __forceinline__ unsigned short f2bf(float f) {
    unsigned u = __float_as_uint(f);
    u = (u + 0x7fffu + ((u >> 16) & 1u)) >> 16;   // RNE
    return (unsigned short)u;
}

// Kernel 1: fold conv into fc1 -> bf16 W1eff [128 n][800 k] (zero-padded),
// and w2 -> bf16 [16 n][128 k] (zero-padded).
__global__ void build_weights(const float* __restrict__ conv_w,
                              const float* __restrict__ w1,
                              const float* __restrict__ w2,
                              unsigned short* __restrict__ w1b,
                              unsigned short* __restrict__ w2b) {
    int idx = blockIdx.x * blockDim.x + threadIdx.x;
    if (idx < 128 * KP) {
        int n = idx / KP, k = idx - n * KP;
        float val = 0.f;
        if (n < HID && k < FLATK) {
            int qr = k / IMG, qc = k % IMG;
            #pragma unroll
            for (int i = 0; i < 3; ++i) {
                int r = qr - i;
                if (r < 0 || r >= OHW) continue;
                #pragma unroll
                for (int j = 0; j < 3; ++j) {
                    int c = qc - j;
                    if (c < 0 || c >= OHW) continue;
                    val += conv_w[i * 3 + j] * w1[n * FLAT + r * OHW + c];
                }
            }
        }
        w1b[idx] = f2bf(val);
    } else {
        int t = idx - 128 * KP;
        if (t < 16 * 128) {
            int n = t >> 7, k = t & 127;
            float v = (n < NCLS && k < HID) ? w2[n * HID + k] : 0.f;
            w2b[t] = f2bf(v);
        }
    }
}

// load step S's A-fragments (both mf rows) into pre[PH] -- PH and S are
// ALWAYS literals, so pre[] SROA-promotes to registers (no scratch).
#define LOADA(PH, S) do {                                                      \
    int k_ = (S) * 32 + (khi << 3);                                            \
    if (k_ >= FLATK) k_ -= FLATK;  /* S=24 pad lanes: in-row garbage, B=0 */   \
    pre[PH][0] = *(const f32x4*)(xr0 + k_);                                    \
    pre[PH][1] = *(const f32x4*)(xr0 + k_ + 4);                                \
    pre[PH][2] = *(const f32x4*)(xr1 + k_);                                    \
    pre[PH][3] = *(const f32x4*)(xr1 + k_ + 4);                                \
} while (0)

// consume step S from pre[PH]: cvt_pk -> 2 A-fragments, 8 B-loads, 16 MFMA
#define COMP(PH, S) do {                                                       \
    union { u32x4 u; bfrag b; } a0_, a1_;                                      \
    asm("v_cvt_pk_bf16_f32 %0, %1, %2" : "=v"(a0_.u.x) : "v"(pre[PH][0].x), "v"(pre[PH][0].y)); \
    asm("v_cvt_pk_bf16_f32 %0, %1, %2" : "=v"(a0_.u.y) : "v"(pre[PH][0].z), "v"(pre[PH][0].w)); \
    asm("v_cvt_pk_bf16_f32 %0, %1, %2" : "=v"(a0_.u.z) : "v"(pre[PH][1].x), "v"(pre[PH][1].y)); \
    asm("v_cvt_pk_bf16_f32 %0, %1, %2" : "=v"(a0_.u.w) : "v"(pre[PH][1].z), "v"(pre[PH][1].w)); \
    asm("v_cvt_pk_bf16_f32 %0, %1, %2" : "=v"(a1_.u.x) : "v"(pre[PH][2].x), "v"(pre[PH][2].y)); \
    asm("v_cvt_pk_bf16_f32 %0, %1, %2" : "=v"(a1_.u.y) : "v"(pre[PH][2].z), "v"(pre[PH][2].w)); \
    asm("v_cvt_pk_bf16_f32 %0, %1, %2" : "=v"(a1_.u.z) : "v"(pre[PH][3].x), "v"(pre[PH][3].y)); \
    asm("v_cvt_pk_bf16_f32 %0, %1, %2" : "=v"(a1_.u.w) : "v"(pre[PH][3].z), "v"(pre[PH][3].w)); \
    _Pragma("unroll")                                                          \
    for (int nt = 0; nt < 8; ++nt) {                                           \
        const bfrag bw = *(const bfrag*)(w1b + (size_t)((nt << 4) + r15) * KP  \
                                         + (S) * 32 + (khi << 3));             \
        acc0[nt] = __builtin_amdgcn_mfma_f32_16x16x32_bf16(a0_.b, bw, acc0[nt], 0, 0, 0); \
        acc1[nt] = __builtin_amdgcn_mfma_f32_16x16x32_bf16(a1_.b, bw, acc1[nt], 0, 0, 0); \
    }                                                                          \
} while (0)

// Kernel 2: barrier-free main loop (no LDS, no syncs, no explicit waitcnt --
// compiler software-pipelines the fully-unrolled load/MFMA stream). 4 waves
// x 32 rows; A global->reg depth-3 ring (literal indices only); B from
// L2-hot w1b shared across the wave's two 16-row tiles. LDS only for h1.
__global__ __launch_bounds__(256) void fused_fwd(
    const float* __restrict__ x,              // [65536][784] f32
    const unsigned short* __restrict__ w1b,   // [128][800] bf16
    const float* __restrict__ b1,             // [100]
    const unsigned short* __restrict__ w2b,   // [16][128] bf16
    const float* __restrict__ b2,             // [10]
    float* __restrict__ out)                  // [65536][10] f32
{
    __shared__ unsigned short H1[BM][136];    // 34816 B, epilogue only

    const int tid  = threadIdx.x;
    const int lane = tid & 63;
    const int wv   = tid >> 6;       // 0..3
    const int r15  = lane & 15;
    const int khi  = lane >> 4;      // 0..3 (k-slice *8)
    const int row0 = blockIdx.x * BM;

    // A rows: lane holds row r15 of mf0 slab and row 16+r15 of mf1 slab
    const float* xr0 = x + (size_t)(row0 + (wv << 5) + r15) * FLATK;
    const float* xr1 = xr0 + 16 * FLATK;

    f32x4 acc0[8], acc1[8];
    #pragma unroll
    for (int n = 0; n < 8; ++n) {
        acc0[n] = f32x4{0.f, 0.f, 0.f, 0.f};
        acc1[n] = f32x4{0.f, 0.f, 0.f, 0.f};
    }

    f32x4 pre[3][4];   // depth-3 prefetch ring, literal indices only

    LOADA(0, 0); LOADA(1, 1); LOADA(2, 2);

    COMP(0, 0);  LOADA(0, 3);   COMP(1, 1);  LOADA(1, 4);   COMP(2, 2);  LOADA(2, 5);
    COMP(0, 3);  LOADA(0, 6);   COMP(1, 4);  LOADA(1, 7);   COMP(2, 5);  LOADA(2, 8);
    COMP(0, 6);  LOADA(0, 9);   COMP(1, 7);  LOADA(1, 10);  COMP(2, 8);  LOADA(2, 11);
    COMP(0, 9);  LOADA(0, 12);  COMP(1, 10); LOADA(1, 13);  COMP(2, 11); LOADA(2, 14);
    COMP(0, 12); LOADA(0, 15);  COMP(1, 13); LOADA(1, 16);  COMP(2, 14); LOADA(2, 17);
    COMP(0, 15); LOADA(0, 18);  COMP(1, 16); LOADA(1, 19);  COMP(2, 17); LOADA(2, 20);
    COMP(0, 18); LOADA(0, 21);  COMP(1, 19); LOADA(1, 22);  COMP(2, 20); LOADA(2, 23);
    COMP(0, 21); LOADA(0, 24);  COMP(1, 22);                COMP(2, 23);
    COMP(0, 24);

    // epilogue 1: bias + relu -> bf16 h1 in LDS [128][136]
    #pragma unroll
    for (int nt = 0; nt < 8; ++nt) {
        int col = (nt << 4) + r15;
        float bias = (col < HID) ? b1[col] : 0.f;
        int rb0 = (wv << 5) + (khi << 2);
        #pragma unroll
        for (int q = 0; q < 4; ++q) {
            float v0 = acc0[nt][q] + bias;
            float v1 = acc1[nt][q] + bias;
            H1[rb0 + q][col]      = f2bf(fmaxf(v0, 0.f));
            H1[rb0 + 16 + q][col] = f2bf(fmaxf(v1, 0.f));
        }
    }
    __syncthreads();

    // layer 2: [128 rows] x [16 cols] over K=128 (pad cols/k are exact zeros)
    f32x4 acc2[2] = {f32x4{0.f,0.f,0.f,0.f}, f32x4{0.f,0.f,0.f,0.f}};
    #pragma unroll
    for (int ks = 0; ks < 4; ++ks) {
        const bfrag bw = *(const bfrag*)(w2b + r15 * 128 + (ks << 5) + (khi << 3));
        #pragma unroll
        for (int mf = 0; mf < 2; ++mf) {
            int r = (wv << 5) + (mf << 4) + r15;
            const bfrag ah = *(const bfrag*)&H1[r][(ks << 5) + (khi << 3)];
            acc2[mf] = __builtin_amdgcn_mfma_f32_16x16x32_bf16(ah, bw, acc2[mf], 0, 0, 0);
        }
    }

    if (r15 < NCLS) {
        float bias2 = b2[r15];
        #pragma unroll
        for (int mf = 0; mf < 2; ++mf) {
            int rbase = row0 + (wv << 5) + (mf << 4) + (khi << 2);
            #pragma unroll
            for (int q = 0; q < 4; ++q)
                out[(size_t)(rbase + q) * NCLS + r15] = acc2[mf][q] + bias2;
        }
    }
}

extern "C" void kernel_launch(void* const* d_in, const int* in_sizes, int n_in,
                              void* d_out, int out_size, void* d_ws, size_t ws_size,
                              hipStream_t stream) {
    const float* x      = (const float*)d_in[0];
    const float* conv_w = (const float*)d_in[1];
    const float* w1     = (const float*)d_in[2];
    const float* b1     = (const float*)d_in[3];
    const float* w2     = (const float*)d_in[4];
    const float* b2     = (const float*)d_in[5];
    float* out = (float*)d_out;

    unsigned short* w1b = (unsigned short*)d_ws;   // 128*800*2 = 204.8 KB
    unsigned short* w2b = w1b + 128 * KP;          // 16*128*2  = 4 KB

    build_weights<<<(128 * KP + 16 * 128 + 255) / 256, 256, 0, stream>>>(conv_w, w1, w2, w1b, w2b);
    fused_fwd<<<65536 / BM, 256, 0, stream>>>(x, w1b, b1, w2b, b2, out);
}